// Round 13
// baseline (191.814 us; speedup 1.0000x reference)
//
#include <hip/hip_runtime.h>
#include <math.h>

#define NEG 0.2f
#define LMAX 1024
#define CAP 1600   // padded per-bucket edge capacity (lambda=1088, >15 sigma)
#define SCHUNK 2048
typedef unsigned short u16;
typedef unsigned int u32;
typedef __bf16 bf16x8 __attribute__((ext_vector_type(8)));
typedef float f32x4 __attribute__((ext_vector_type(4)));

__device__ __forceinline__ float bf2f(u16 u) {
    union { unsigned i; float f; } x; x.i = ((unsigned)u) << 16; return x.f;
}
__device__ __forceinline__ u16 f2bf(float f) {
    union { float f; unsigned u; } x; x.f = f;
    unsigned r = x.u + 0x7fffu + ((x.u >> 16) & 1u);
    return (u16)(r >> 16);
}

// ---------------- prep: W1x (272x256 bf16, att folded) + W2x + zero bktcur -----
__global__ void prep_all(const float* __restrict__ W1, const float* __restrict__ att_s1,
                         const float* __restrict__ att_d1, u16* __restrict__ w1x,
                         const float* __restrict__ W2, const float* __restrict__ att_s2,
                         const float* __restrict__ att_d2, u16* __restrict__ w2x,
                         int* __restrict__ bktcur, int NBK) {
    int t = threadIdx.x;
    if (blockIdx.x < 256) {
        int k = blockIdx.x;        // 0..255
        int c = t;                 // 0..255
        float w = W1[k * 256 + c];
        w1x[c * 256 + k] = f2bf(w);
        int head = c >> 6;
        float vs = w * att_s1[c];
        float vd = w * att_d1[c];
#pragma unroll
        for (int mask = 1; mask < 64; mask <<= 1) {
            vs += __shfl_xor(vs, mask, 64);
            vd += __shfl_xor(vd, mask, 64);
        }
        if ((c & 63) == 0) {
            w1x[(256 + head) * 256 + k] = f2bf(vs);
            w1x[(260 + head) * 256 + k] = f2bf(vd);
            w1x[(264 + head) * 256 + k] = 0;
            w1x[(268 + head) * 256 + k] = 0;
        }
    } else {
        // w2x[j][k] = W2[k][j]; row 32 = A2s, 33 = A2d, 34..47 = 0
        int k = t;
        float a_s = 0.f, a_d = 0.f;
#pragma unroll
        for (int j = 0; j < 32; ++j) {
            float w = W2[k * 32 + j];
            w2x[j * 256 + k] = f2bf(w);
            a_s += w * att_s2[j];
            a_d += w * att_d2[j];
        }
        w2x[32 * 256 + k] = f2bf(a_s);
        w2x[33 * 256 + k] = f2bf(a_d);
#pragma unroll
        for (int r = 34; r < 48; ++r) w2x[r * 256 + k] = 0;
        for (int i = t; i < NBK; i += 256) bktcur[i] = 0;
    }
}

// ---------------- fused: GEMM1 (blocks 0..255) + edge scatter (blocks 256+) ------
__global__ __launch_bounds__(512) void gemm1_and_scatter(
        const float* __restrict__ x, const u16* __restrict__ w1x,
        u16* __restrict__ h1b, float* __restrict__ asad, int N,
        const int* __restrict__ ei, int* __restrict__ bktcur,
        u32* __restrict__ ebuf, int E, int ET, int NBK) {
    __shared__ __align__(16) u16 xs[2][16][264];
    __shared__ int lcnt[LMAX];
    __shared__ int lbase[LMAX];
    int t = threadIdx.x;

    if (blockIdx.x < 256) {
        // ---- gemm1 path ----
        int wave = t >> 6, lane = t & 63;
        int g = lane >> 4, l15 = lane & 15;

        bf16x8 wreg[3][8];
#pragma unroll
        for (int ci = 0; ci < 3; ++ci) {
            int ct = (ci == 2) ? 16 : (wave * 2 + ci);
            const u16* wp = w1x + (size_t)(ct * 16 + l15) * 256 + g * 8;
#pragma unroll
            for (int ks = 0; ks < 8; ++ks)
                wreg[ci][ks] = *reinterpret_cast<const bf16x8*>(wp + ks * 32);
        }

        int srow = t >> 5, sseg = t & 31;
        int ntiles = (N + 15) >> 4;
        int tile0 = blockIdx.x;
        if (tile0 >= ntiles) return;

        auto stage_load = [&](int tile, float4& a0, float4& a1) {
            int arow = tile * 16 + srow; if (arow > N - 1) arow = N - 1;
            const float* xp = x + (size_t)arow * 256 + sseg * 8;
            a0 = *reinterpret_cast<const float4*>(xp);
            a1 = *reinterpret_cast<const float4*>(xp + 4);
        };
        auto stage_write = [&](int buf, const float4& a0, const float4& a1) {
            uint4 o;
            o.x = (unsigned)f2bf(a0.x) | ((unsigned)f2bf(a0.y) << 16);
            o.y = (unsigned)f2bf(a0.z) | ((unsigned)f2bf(a0.w) << 16);
            o.z = (unsigned)f2bf(a1.x) | ((unsigned)f2bf(a1.y) << 16);
            o.w = (unsigned)f2bf(a1.z) | ((unsigned)f2bf(a1.w) << 16);
            *reinterpret_cast<uint4*>(&xs[buf][srow][sseg * 8]) = o;
        };

        {
            float4 a0, a1;
            stage_load(tile0, a0, a1);
            stage_write(0, a0, a1);
        }
        __syncthreads();

        int cur = 0;
        for (int tile = tile0; tile < ntiles; tile += 256) {
            int nxt = tile + 256;
            bool hasnext = nxt < ntiles;
            float4 p0, p1;
            if (hasnext) stage_load(nxt, p0, p1);

            f32x4 acc[3];
#pragma unroll
            for (int ci = 0; ci < 3; ++ci) acc[ci] = (f32x4){0.f, 0.f, 0.f, 0.f};
#pragma unroll
            for (int ks = 0; ks < 8; ++ks) {
                bf16x8 bfr = *reinterpret_cast<const bf16x8*>(&xs[cur][l15][ks * 32 + g * 8]);
#pragma unroll
                for (int ci = 0; ci < 3; ++ci)
                    acc[ci] = __builtin_amdgcn_mfma_f32_16x16x32_bf16(wreg[ci][ks], bfr, acc[ci], 0, 0, 0);
            }

            int nrow = tile * 16 + l15;
            if (nrow < N) {
#pragma unroll
                for (int ci = 0; ci < 2; ++ci) {
                    int ct = wave * 2 + ci;
                    ushort4 o;
                    o.x = f2bf(acc[ci][0]); o.y = f2bf(acc[ci][1]);
                    o.z = f2bf(acc[ci][2]); o.w = f2bf(acc[ci][3]);
                    *reinterpret_cast<ushort4*>(h1b + (size_t)nrow * 256 + ct * 16 + g * 4) = o;
                }
                if (wave == 0 && g < 2) {
#pragma unroll
                    for (int reg = 0; reg < 4; ++reg)
                        asad[(size_t)nrow * 8 + g * 4 + reg] = acc[2][reg];
                }
            }
            __syncthreads();
            if (hasnext) stage_write(cur ^ 1, p0, p1);
            __syncthreads();
            cur ^= 1;
        }
    } else {
        // ---- scatter path ----
        int cb = blockIdx.x - 256;
        for (int b = t; b < NBK; b += 512) lcnt[b] = 0;
        __syncthreads();
        int base = cb * SCHUNK;
#pragma unroll
        for (int k = 0; k < SCHUNK / 512; ++k) {
            int i = base + k * 512 + t;
            if (i < ET) {
                int d = (i < E) ? ei[E + i] : (i - E);
                atomicAdd(&lcnt[d >> 6], 1);
            }
        }
        __syncthreads();
        for (int b = t; b < NBK; b += 512) {
            int c = lcnt[b];
            lbase[b] = c ? (b * CAP + atomicAdd(&bktcur[b], c)) : 0;
        }
        __syncthreads();
        for (int b = t; b < NBK; b += 512) lcnt[b] = 0;
        __syncthreads();
#pragma unroll
        for (int k = 0; k < SCHUNK / 512; ++k) {
            int i = base + k * 512 + t;
            if (i < ET) {
                int s, d;
                if (i < E) { s = ei[i]; d = ei[E + i]; }
                else       { s = i - E; d = s; }
                int b = d >> 6;
                int idx = atomicAdd(&lcnt[b], 1);
                ebuf[lbase[b] + idx] = (u32)s | ((u32)(d & 63) << 16);
            }
        }
    }
}

// ---------------- per bucket: LDS count, wave scan -> row_ptr/rowend, fill col ---
__global__ __launch_bounds__(256) void bucket_csr_pad(const u32* __restrict__ ebuf,
                                                      const int* __restrict__ bktcur,
                                                      int* __restrict__ row_ptr,
                                                      int* __restrict__ rowend,
                                                      int* __restrict__ col, int N) {
    __shared__ int cnt[64];
    __shared__ int cur[64];
    int b = blockIdx.x, t = threadIdx.x;
    int v0 = b << 6;
    int s0 = b * CAP, s1 = s0 + bktcur[b];
    if (t < 64) cnt[t] = 0;
    __syncthreads();
    for (int i = s0 + t; i < s1; i += 256)
        atomicAdd(&cnt[(ebuf[i] >> 16) & 63], 1);
    __syncthreads();
    if (t < 64) {
        int c = cnt[t];
        int val = c;
#pragma unroll
        for (int off = 1; off < 64; off <<= 1) {
            int n = __shfl_up(val, off, 64);
            if (t >= off) val += n;
        }
        int excl = s0 + val - c;
        if (v0 + t < N) { row_ptr[v0 + t] = excl; rowend[v0 + t] = excl + c; }
        cur[t] = excl;
    }
    __syncthreads();
    for (int i = s0 + t; i < s1; i += 256) {
        u32 v = ebuf[i];
        int pos = atomicAdd(&cur[(v >> 16) & 63], 1);
        col[pos] = (int)(v & 0xFFFFu);
    }
}

// ---------------- conv1 fused + per-block gemm2 epilogue ----------------
// stats sweep caches alpha+col in LDS; gather; relu'd rows -> LDS; 3 waves run
// one 16x16x32 MFMA n-tile each vs w2x (L2) -> h2b cols 0..31, as2/ad2.
__global__ __launch_bounds__(256) void conv1_g2(const u16* __restrict__ h1b,
                                                const float* __restrict__ asad,
                                                const int* __restrict__ row_ptr,
                                                const int* __restrict__ rowend,
                                                const int* __restrict__ col,
                                                const float* __restrict__ b1,
                                                const u16* __restrict__ w2x,
                                                u16* __restrict__ h2b,
                                                float* __restrict__ as2,
                                                float* __restrict__ ad2, int N) {
    __shared__ float la[4][128][4];
    __shared__ int   lc[4][128];
    __shared__ __align__(16) u16 rows[4][268];   // stride 268: <=2-way on frag reads
    int idx = blockIdx.x * blockDim.x + threadIdx.x;
    int v = idx >> 6; if (v > N - 1) v = N - 1;
    int lane = idx & 63;
    int node = threadIdx.x >> 6;
    int head = lane >> 4, l15 = lane & 15;
    float adst = asad[(size_t)v * 8 + 4 + head];
    int beg = row_ptr[v], end = rowend[v];
    int deg = end - beg;
    bool fast = (deg <= 128);
    float m = -1e30f, l = 0.f;
    if (fast) {
        float e[8]; int u[8];
#pragma unroll
        for (int i = 0; i < 8; ++i) {
            int p = beg + l15 + i * 16;
            float ev = -1e30f; int uu = 0;
            if (p < end) {
                uu = col[p];
                float tv = asad[(size_t)uu * 8 + head] + adst;
                ev = tv > 0.f ? tv : NEG * tv;
            }
            e[i] = ev; u[i] = uu;
        }
        m = e[0];
#pragma unroll
        for (int i = 1; i < 8; ++i) m = fmaxf(m, e[i]);
#pragma unroll
        for (int mask = 1; mask < 16; mask <<= 1) m = fmaxf(m, __shfl_xor(m, mask, 64));
#pragma unroll
        for (int i = 0; i < 8; ++i) {
            int j = l15 + i * 16;
            if (beg + j < end) {
                float a = __expf(e[i] - m);
                l += a;
                la[node][j][head] = a;
                if (head == 0) lc[node][j] = u[i];
            }
        }
#pragma unroll
        for (int mask = 1; mask < 16; mask <<= 1) l += __shfl_xor(l, mask, 64);
    } else {
        for (int p = beg + l15; p < end; p += 16) {
            float tv = asad[(size_t)col[p] * 8 + head] + adst;
            tv = tv > 0.f ? tv : NEG * tv;
            m = fmaxf(m, tv);
        }
#pragma unroll
        for (int mask = 1; mask < 16; mask <<= 1) m = fmaxf(m, __shfl_xor(m, mask, 64));
        for (int p = beg + l15; p < end; p += 16) {
            float tv = asad[(size_t)col[p] * 8 + head] + adst;
            tv = tv > 0.f ? tv : NEG * tv;
            l += __expf(tv - m);
        }
#pragma unroll
        for (int mask = 1; mask < 16; mask <<= 1) l += __shfl_xor(l, mask, 64);
    }
    __syncthreads();
    float inv = 1.f / (l + 1e-16f);

    float ax = 0.f, ay = 0.f, az = 0.f, aw = 0.f;
    if (fast) {
        int j = 0;
        for (; j + 3 < deg; j += 4) {
            float a0 = la[node][j + 0][head];
            float a1 = la[node][j + 1][head];
            float a2 = la[node][j + 2][head];
            float a3 = la[node][j + 3][head];
            int u0 = lc[node][j + 0], u1 = lc[node][j + 1];
            int u2 = lc[node][j + 2], u3 = lc[node][j + 3];
            ushort4 h0 = *reinterpret_cast<const ushort4*>(h1b + (size_t)u0 * 256 + lane * 4);
            ushort4 h1 = *reinterpret_cast<const ushort4*>(h1b + (size_t)u1 * 256 + lane * 4);
            ushort4 h2 = *reinterpret_cast<const ushort4*>(h1b + (size_t)u2 * 256 + lane * 4);
            ushort4 h3 = *reinterpret_cast<const ushort4*>(h1b + (size_t)u3 * 256 + lane * 4);
            ax += a0 * bf2f(h0.x) + a1 * bf2f(h1.x) + a2 * bf2f(h2.x) + a3 * bf2f(h3.x);
            ay += a0 * bf2f(h0.y) + a1 * bf2f(h1.y) + a2 * bf2f(h2.y) + a3 * bf2f(h3.y);
            az += a0 * bf2f(h0.z) + a1 * bf2f(h1.z) + a2 * bf2f(h2.z) + a3 * bf2f(h3.z);
            aw += a0 * bf2f(h0.w) + a1 * bf2f(h1.w) + a2 * bf2f(h2.w) + a3 * bf2f(h3.w);
        }
        for (; j < deg; ++j) {
            float a = la[node][j][head];
            int u = lc[node][j];
            ushort4 hv = *reinterpret_cast<const ushort4*>(h1b + (size_t)u * 256 + lane * 4);
            ax += a * bf2f(hv.x);
            ay += a * bf2f(hv.y);
            az += a * bf2f(hv.z);
            aw += a * bf2f(hv.w);
        }
    } else {
        for (int p = beg; p < end; ++p) {
            int u = col[p];
            float tv = asad[(size_t)u * 8 + head] + adst;
            tv = tv > 0.f ? tv : NEG * tv;
            float a = __expf(tv - m);
            ushort4 hv = *reinterpret_cast<const ushort4*>(h1b + (size_t)u * 256 + lane * 4);
            ax += a * bf2f(hv.x);
            ay += a * bf2f(hv.y);
            az += a * bf2f(hv.z);
            aw += a * bf2f(hv.w);
        }
    }
    int c = lane * 4;
    ushort4 o;
    o.x = f2bf(fmaxf(ax * inv + b1[c + 0], 0.f));
    o.y = f2bf(fmaxf(ay * inv + b1[c + 1], 0.f));
    o.z = f2bf(fmaxf(az * inv + b1[c + 2], 0.f));
    o.w = f2bf(fmaxf(aw * inv + b1[c + 3], 0.f));
    *reinterpret_cast<ushort4*>(&rows[node][lane * 4]) = o;
    __syncthreads();

    // gemm2 epilogue: wave wv (0..2) computes n-tile wv of [4 nodes] x w2x^T
    int wv = threadIdx.x >> 6;
    if (wv < 3) {
        int g = lane >> 4;
        f32x4 acc = (f32x4){0.f, 0.f, 0.f, 0.f};
        const u16* wp = w2x + (size_t)(wv * 16 + l15) * 256 + g * 8;
#pragma unroll
        for (int ks = 0; ks < 8; ++ks) {
            bf16x8 af = *reinterpret_cast<const bf16x8*>(&rows[l15 & 3][ks * 32 + g * 8]);
            bf16x8 bf = *reinterpret_cast<const bf16x8*>(wp + ks * 32);
            acc = __builtin_amdgcn_mfma_f32_16x16x32_bf16(af, bf, acc, 0, 0, 0);
        }
        // D: node m = g*4+reg (valid m<4 -> g==0), channel = wv*16+l15
        if (g == 0) {
            int vbase = blockIdx.x * 4;
            if (wv < 2) {
#pragma unroll
                for (int reg = 0; reg < 4; ++reg) {
                    int n = vbase + reg;
                    if (n < N) h2b[(size_t)n * 32 + wv * 16 + l15] = f2bf(acc[reg]);
                }
            } else {
                if (l15 == 0) {
#pragma unroll
                    for (int reg = 0; reg < 4; ++reg) {
                        int n = vbase + reg;
                        if (n < N) as2[n] = acc[reg];
                    }
                }
                if (l15 == 1) {
#pragma unroll
                    for (int reg = 0; reg < 4; ++reg) {
                        int n = vbase + reg;
                        if (n < N) ad2[n] = acc[reg];
                    }
                }
            }
        }
    }
}

// ---------------- conv2 fused: stats caches alpha+col in LDS, then gather --------
__global__ __launch_bounds__(256) void conv2_fused(const u16* __restrict__ h2b,
                                                   const float* __restrict__ as2,
                                                   const float* __restrict__ ad2,
                                                   const int* __restrict__ row_ptr,
                                                   const int* __restrict__ rowend,
                                                   const int* __restrict__ col,
                                                   const float* __restrict__ b2,
                                                   float* __restrict__ out2, int N) {
    __shared__ float la[8][128];
    __shared__ int   lc[8][128];
    int idx = blockIdx.x * blockDim.x + threadIdx.x;
    int v = idx >> 5; if (v > N - 1) v = N - 1;
    int lane = idx & 31;
    int node = threadIdx.x >> 5;
    float adst = ad2[v];
    int beg = row_ptr[v], end = rowend[v];
    int deg = end - beg;
    bool fast = (deg <= 128);
    float m = -1e30f, l = 0.f;
    if (fast) {
        float e[4]; int u[4];
#pragma unroll
        for (int i = 0; i < 4; ++i) {
            int p = beg + lane + i * 32;
            float ev = -1e30f; int uu = 0;
            if (p < end) {
                uu = col[p];
                float tv = as2[uu] + adst;
                ev = tv > 0.f ? tv : NEG * tv;
            }
            e[i] = ev; u[i] = uu;
        }
        m = fmaxf(fmaxf(e[0], e[1]), fmaxf(e[2], e[3]));
#pragma unroll
        for (int mask = 1; mask < 32; mask <<= 1) m = fmaxf(m, __shfl_xor(m, mask, 64));
#pragma unroll
        for (int i = 0; i < 4; ++i) {
            int j = lane + i * 32;
            if (beg + j < end) {
                float a = __expf(e[i] - m);
                l += a;
                la[node][j] = a;
                lc[node][j] = u[i];
            }
        }
#pragma unroll
        for (int mask = 1; mask < 32; mask <<= 1) l += __shfl_xor(l, mask, 64);
    } else {
        for (int p = beg + lane; p < end; p += 32) {
            float tv = as2[col[p]] + adst;
            tv = tv > 0.f ? tv : NEG * tv;
            m = fmaxf(m, tv);
        }
#pragma unroll
        for (int mask = 1; mask < 32; mask <<= 1) m = fmaxf(m, __shfl_xor(m, mask, 64));
        for (int p = beg + lane; p < end; p += 32) {
            float tv = as2[col[p]] + adst;
            tv = tv > 0.f ? tv : NEG * tv;
            l += __expf(tv - m);
        }
#pragma unroll
        for (int mask = 1; mask < 32; mask <<= 1) l += __shfl_xor(l, mask, 64);
    }
    __syncthreads();
    float inv = 1.f / (l + 1e-16f);

    float acc = 0.f;
    if (fast) {
        int j = 0;
        for (; j + 3 < deg; j += 4) {
            float a0 = la[node][j + 0], a1 = la[node][j + 1];
            float a2 = la[node][j + 2], a3 = la[node][j + 3];
            int u0 = lc[node][j + 0], u1 = lc[node][j + 1];
            int u2 = lc[node][j + 2], u3 = lc[node][j + 3];
            acc += a0 * bf2f(h2b[(size_t)u0 * 32 + lane])
                 + a1 * bf2f(h2b[(size_t)u1 * 32 + lane])
                 + a2 * bf2f(h2b[(size_t)u2 * 32 + lane])
                 + a3 * bf2f(h2b[(size_t)u3 * 32 + lane]);
        }
        for (; j < deg; ++j)
            acc += la[node][j] * bf2f(h2b[(size_t)lc[node][j] * 32 + lane]);
    } else {
        for (int p = beg; p < end; ++p) {
            int u = col[p];
            float tv = as2[u] + adst;
            tv = tv > 0.f ? tv : NEG * tv;
            acc += __expf(tv - m) * bf2f(h2b[(size_t)u * 32 + lane]);
        }
    }
    out2[(size_t)v * 32 + lane] = acc * inv + b2[lane];
}

// ---------------- pooling + FC head ----------------
__global__ __launch_bounds__(256) void pool_fc(const float* __restrict__ out2,
                                               const int* __restrict__ batch,
                                               const float* __restrict__ fc1w,
                                               const float* __restrict__ fc1b,
                                               const float* __restrict__ fc2w,
                                               const float* __restrict__ fc2b,
                                               float* __restrict__ out, int N) {
    int g = blockIdx.x;
    int lo = 0, hi = N;
    while (lo < hi) { int mid = (lo + hi) >> 1; if (batch[mid] < g) lo = mid + 1; else hi = mid; }
    int s = lo;
    lo = 0; hi = N;
    while (lo < hi) { int mid = (lo + hi) >> 1; if (batch[mid] < g + 1) lo = mid + 1; else hi = mid; }
    int e = lo;

    int c = threadIdx.x & 31, grp = threadIdx.x >> 5;
    float sum = 0.f;
    for (int r = s + grp; r < e; r += 8) sum += out2[(size_t)r * 32 + c];
    __shared__ float part[8][32];
    part[grp][c] = sum;
    __syncthreads();
    __shared__ float g0[32];
    if (grp == 0) {
        float tot = 0.f;
#pragma unroll
        for (int q = 0; q < 8; ++q) tot += part[q][c];
        float cnt = (float)(e - s);
        g0[c] = fmaxf(tot / fmaxf(cnt, 1.0f), 0.f);
    }
    __syncthreads();
    __shared__ float z1[16];
    if (threadIdx.x < 16) {
        float a = fc1b[threadIdx.x];
        for (int k = 0; k < 32; ++k) a += g0[k] * fc1w[k * 16 + threadIdx.x];
        z1[threadIdx.x] = fmaxf(a, 0.f);
    }
    __syncthreads();
    if (threadIdx.x < 16) {
        float a = fc2b[threadIdx.x];
        for (int k = 0; k < 16; ++k) a += z1[k] * fc2w[k * 16 + threadIdx.x];
        out[g * 16 + threadIdx.x] = fmaxf(a, 0.f);
    }
}

// ---------------- host launcher ----------------
extern "C" void kernel_launch(void* const* d_in, const int* in_sizes, int n_in,
                              void* d_out, int out_size, void* d_ws, size_t ws_size,
                              hipStream_t stream) {
    const float* x      = (const float*)d_in[0];
    const int*   ei     = (const int*)d_in[1];
    const int*   batch  = (const int*)d_in[2];
    const float* W1     = (const float*)d_in[3];
    const float* att_s1 = (const float*)d_in[4];
    const float* att_d1 = (const float*)d_in[5];
    const float* b1     = (const float*)d_in[6];
    const float* W2     = (const float*)d_in[7];
    const float* att_s2 = (const float*)d_in[8];
    const float* att_d2 = (const float*)d_in[9];
    const float* b2     = (const float*)d_in[10];
    const float* fc1w   = (const float*)d_in[11];
    const float* fc1b   = (const float*)d_in[12];
    const float* fc2w   = (const float*)d_in[13];
    const float* fc2b   = (const float*)d_in[14];
    float* out = (float*)d_out;

    int N = in_sizes[0] / 256;      // 50000
    int E = in_sizes[1] / 2;        // 800000
    int ET = E + N;
    int NBK = (N + 63) >> 6;        // 782
    int nchunks = (ET + SCHUNK - 1) / SCHUNK;   // 416

    char* ws = (char*)d_ws;
    size_t off = 0;
    auto alloc = [&](size_t bytes) { size_t o = off; off = (off + bytes + 255) & ~255ULL; return o; };
    u16*  w1x    = (u16*)(ws + alloc(272 * 256 * 2));
    u16*  w2x    = (u16*)(ws + alloc(48 * 256 * 2));
    u16*  h1b    = (u16*)(ws + alloc((size_t)N * 256 * 2));
    float* asad  = (float*)(ws + alloc((size_t)N * 8 * 4));
    u16*  h2b    = (u16*)(ws + alloc((size_t)N * 32 * 2));
    float* as2   = (float*)(ws + alloc((size_t)N * 4));
    float* ad2   = (float*)(ws + alloc((size_t)N * 4));
    float* out2  = (float*)(ws + alloc((size_t)N * 32 * 4));
    int* row_ptr = (int*)(ws + alloc((size_t)N * 4));
    int* rowend  = (int*)(ws + alloc((size_t)N * 4));
    int* col     = (int*)(ws + alloc((size_t)NBK * CAP * 4));
    int* bktcur  = (int*)(ws + alloc((size_t)NBK * 4));
    u32* ebuf    = (u32*)(ws + alloc((size_t)NBK * CAP * 4));
    (void)ws_size; (void)n_in; (void)out_size;

    // prep: w1x + w2x + zero bktcur
    prep_all<<<257, 256, 0, stream>>>(W1, att_s1, att_d1, w1x, W2, att_s2, att_d2, w2x, bktcur, NBK);

    // fused gemm1 + edge scatter (mutually independent work, co-scheduled)
    gemm1_and_scatter<<<256 + nchunks, 512, 0, stream>>>(x, w1x, h1b, asad, N,
                                                         ei, bktcur, ebuf, E, ET, NBK);

    // per-bucket CSR finalize
    bucket_csr_pad<<<NBK, 256, 0, stream>>>(ebuf, bktcur, row_ptr, rowend, col, N);

    // conv1 + fused per-block gemm2 (produces h2b/as2/ad2 directly; no hin2b)
    conv1_g2<<<(N * 64 + 255) / 256, 256, 0, stream>>>(h1b, asad, row_ptr, rowend, col, b1,
                                                       w2x, h2b, as2, ad2, N);

    // conv2
    conv2_fused<<<(N * 32 + 255) / 256, 256, 0, stream>>>(h2b, as2, ad2, row_ptr, rowend, col, b2, out2, N);

    // pool + fc
    pool_fc<<<64, 256, 0, stream>>>(out2, batch, fc1w, fc1b, fc2w, fc2b, out, N);
}

// Round 14
// 180.972 us; speedup vs baseline: 1.0599x; 1.0599x over previous
//
#include <hip/hip_runtime.h>
#include <math.h>

#define NEG 0.2f
#define LMAX 1024
#define CAP 1600   // padded per-bucket edge capacity (lambda=1088, >15 sigma)
#define SCHUNK 2048
typedef unsigned short u16;
typedef unsigned int u32;
typedef __bf16 bf16x8 __attribute__((ext_vector_type(8)));
typedef float f32x4 __attribute__((ext_vector_type(4)));

__device__ __forceinline__ float bf2f(u16 u) {
    union { unsigned i; float f; } x; x.i = ((unsigned)u) << 16; return x.f;
}
__device__ __forceinline__ u16 f2bf(float f) {
    union { float f; unsigned u; } x; x.f = f;
    unsigned r = x.u + 0x7fffu + ((x.u >> 16) & 1u);
    return (u16)(r >> 16);
}

// ---------------- prep: W1x (272x256 bf16, att folded) + W2x + zero bktcur -----
__global__ void prep_all(const float* __restrict__ W1, const float* __restrict__ att_s1,
                         const float* __restrict__ att_d1, u16* __restrict__ w1x,
                         const float* __restrict__ W2, const float* __restrict__ att_s2,
                         const float* __restrict__ att_d2, u16* __restrict__ w2x,
                         int* __restrict__ bktcur, int NBK) {
    int t = threadIdx.x;
    if (blockIdx.x < 256) {
        int k = blockIdx.x;        // 0..255
        int c = t;                 // 0..255
        float w = W1[k * 256 + c];
        w1x[c * 256 + k] = f2bf(w);
        int head = c >> 6;
        float vs = w * att_s1[c];
        float vd = w * att_d1[c];
#pragma unroll
        for (int mask = 1; mask < 64; mask <<= 1) {
            vs += __shfl_xor(vs, mask, 64);
            vd += __shfl_xor(vd, mask, 64);
        }
        if ((c & 63) == 0) {
            w1x[(256 + head) * 256 + k] = f2bf(vs);
            w1x[(260 + head) * 256 + k] = f2bf(vd);
            w1x[(264 + head) * 256 + k] = 0;
            w1x[(268 + head) * 256 + k] = 0;
        }
    } else {
        // w2x[j][k] = W2[k][j]; row 32 = A2s, 33 = A2d, 34..47 = 0
        int k = t;
        float a_s = 0.f, a_d = 0.f;
#pragma unroll
        for (int j = 0; j < 32; ++j) {
            float w = W2[k * 32 + j];
            w2x[j * 256 + k] = f2bf(w);
            a_s += w * att_s2[j];
            a_d += w * att_d2[j];
        }
        w2x[32 * 256 + k] = f2bf(a_s);
        w2x[33 * 256 + k] = f2bf(a_d);
#pragma unroll
        for (int r = 34; r < 48; ++r) w2x[r * 256 + k] = 0;
        for (int i = t; i < NBK; i += 256) bktcur[i] = 0;
    }
}

// ---------------- fused: GEMM1 (blocks 0..255) + edge scatter (blocks 256+) ------
// gemm1: W in registers, x staged through LDS dbuf; wave w owns col-tiles 2w,2w+1
// + att tile 16 (stored by wave 0). scatter: 2048-edge chunks, LDS-aggregated
// bucket runs -> ebuf packed u32 = src | (dst&63)<<16.
__global__ __launch_bounds__(512) void gemm1_and_scatter(
        const float* __restrict__ x, const u16* __restrict__ w1x,
        u16* __restrict__ h1b, float* __restrict__ asad, int N,
        const int* __restrict__ ei, int* __restrict__ bktcur,
        u32* __restrict__ ebuf, int E, int ET, int NBK) {
    __shared__ __align__(16) u16 xs[2][16][264];
    __shared__ int lcnt[LMAX];
    __shared__ int lbase[LMAX];
    int t = threadIdx.x;

    if (blockIdx.x < 256) {
        // ---- gemm1 path ----
        int wave = t >> 6, lane = t & 63;
        int g = lane >> 4, l15 = lane & 15;

        bf16x8 wreg[3][8];
#pragma unroll
        for (int ci = 0; ci < 3; ++ci) {
            int ct = (ci == 2) ? 16 : (wave * 2 + ci);
            const u16* wp = w1x + (size_t)(ct * 16 + l15) * 256 + g * 8;
#pragma unroll
            for (int ks = 0; ks < 8; ++ks)
                wreg[ci][ks] = *reinterpret_cast<const bf16x8*>(wp + ks * 32);
        }

        int srow = t >> 5, sseg = t & 31;
        int ntiles = (N + 15) >> 4;
        int tile0 = blockIdx.x;
        if (tile0 >= ntiles) return;

        auto stage_load = [&](int tile, float4& a0, float4& a1) {
            int arow = tile * 16 + srow; if (arow > N - 1) arow = N - 1;
            const float* xp = x + (size_t)arow * 256 + sseg * 8;
            a0 = *reinterpret_cast<const float4*>(xp);
            a1 = *reinterpret_cast<const float4*>(xp + 4);
        };
        auto stage_write = [&](int buf, const float4& a0, const float4& a1) {
            uint4 o;
            o.x = (unsigned)f2bf(a0.x) | ((unsigned)f2bf(a0.y) << 16);
            o.y = (unsigned)f2bf(a0.z) | ((unsigned)f2bf(a0.w) << 16);
            o.z = (unsigned)f2bf(a1.x) | ((unsigned)f2bf(a1.y) << 16);
            o.w = (unsigned)f2bf(a1.z) | ((unsigned)f2bf(a1.w) << 16);
            *reinterpret_cast<uint4*>(&xs[buf][srow][sseg * 8]) = o;
        };

        {
            float4 a0, a1;
            stage_load(tile0, a0, a1);
            stage_write(0, a0, a1);
        }
        __syncthreads();

        int cur = 0;
        for (int tile = tile0; tile < ntiles; tile += 256) {
            int nxt = tile + 256;
            bool hasnext = nxt < ntiles;
            float4 p0, p1;
            if (hasnext) stage_load(nxt, p0, p1);

            f32x4 acc[3];
#pragma unroll
            for (int ci = 0; ci < 3; ++ci) acc[ci] = (f32x4){0.f, 0.f, 0.f, 0.f};
#pragma unroll
            for (int ks = 0; ks < 8; ++ks) {
                bf16x8 bfr = *reinterpret_cast<const bf16x8*>(&xs[cur][l15][ks * 32 + g * 8]);
#pragma unroll
                for (int ci = 0; ci < 3; ++ci)
                    acc[ci] = __builtin_amdgcn_mfma_f32_16x16x32_bf16(wreg[ci][ks], bfr, acc[ci], 0, 0, 0);
            }

            int nrow = tile * 16 + l15;
            if (nrow < N) {
#pragma unroll
                for (int ci = 0; ci < 2; ++ci) {
                    int ct = wave * 2 + ci;
                    ushort4 o;
                    o.x = f2bf(acc[ci][0]); o.y = f2bf(acc[ci][1]);
                    o.z = f2bf(acc[ci][2]); o.w = f2bf(acc[ci][3]);
                    *reinterpret_cast<ushort4*>(h1b + (size_t)nrow * 256 + ct * 16 + g * 4) = o;
                }
                if (wave == 0 && g < 2) {
#pragma unroll
                    for (int reg = 0; reg < 4; ++reg)
                        asad[(size_t)nrow * 8 + g * 4 + reg] = acc[2][reg];
                }
            }
            __syncthreads();
            if (hasnext) stage_write(cur ^ 1, p0, p1);
            __syncthreads();
            cur ^= 1;
        }
    } else {
        // ---- scatter path ----
        int cb = blockIdx.x - 256;
        for (int b = t; b < NBK; b += 512) lcnt[b] = 0;
        __syncthreads();
        int base = cb * SCHUNK;
#pragma unroll
        for (int k = 0; k < SCHUNK / 512; ++k) {
            int i = base + k * 512 + t;
            if (i < ET) {
                int d = (i < E) ? ei[E + i] : (i - E);
                atomicAdd(&lcnt[d >> 6], 1);
            }
        }
        __syncthreads();
        for (int b = t; b < NBK; b += 512) {
            int c = lcnt[b];
            lbase[b] = c ? (b * CAP + atomicAdd(&bktcur[b], c)) : 0;
        }
        __syncthreads();
        for (int b = t; b < NBK; b += 512) lcnt[b] = 0;
        __syncthreads();
#pragma unroll
        for (int k = 0; k < SCHUNK / 512; ++k) {
            int i = base + k * 512 + t;
            if (i < ET) {
                int s, d;
                if (i < E) { s = ei[i]; d = ei[E + i]; }
                else       { s = i - E; d = s; }
                int b = d >> 6;
                int idx = atomicAdd(&lcnt[b], 1);
                ebuf[lbase[b] + idx] = (u32)s | ((u32)(d & 63) << 16);
            }
        }
    }
}

// ---------------- per bucket: LDS count, wave scan -> row_ptr/rowend, fill col ---
__global__ __launch_bounds__(256) void bucket_csr_pad(const u32* __restrict__ ebuf,
                                                      const int* __restrict__ bktcur,
                                                      int* __restrict__ row_ptr,
                                                      int* __restrict__ rowend,
                                                      int* __restrict__ col, int N) {
    __shared__ int cnt[64];
    __shared__ int cur[64];
    int b = blockIdx.x, t = threadIdx.x;
    int v0 = b << 6;
    int s0 = b * CAP, s1 = s0 + bktcur[b];
    if (t < 64) cnt[t] = 0;
    __syncthreads();
    for (int i = s0 + t; i < s1; i += 256)
        atomicAdd(&cnt[(ebuf[i] >> 16) & 63], 1);
    __syncthreads();
    if (t < 64) {
        int c = cnt[t];
        int val = c;
#pragma unroll
        for (int off = 1; off < 64; off <<= 1) {
            int n = __shfl_up(val, off, 64);
            if (t >= off) val += n;
        }
        int excl = s0 + val - c;
        if (v0 + t < N) { row_ptr[v0 + t] = excl; rowend[v0 + t] = excl + c; }
        cur[t] = excl;
    }
    __syncthreads();
    for (int i = s0 + t; i < s1; i += 256) {
        u32 v = ebuf[i];
        int pos = atomicAdd(&cur[(v >> 16) & 63], 1);
        col[pos] = (int)(v & 0xFFFFu);
    }
}

// ---------------- conv1 fused: stats sweep caches alpha+col in LDS, then gather ---
__global__ __launch_bounds__(256) void conv1_fused(const u16* __restrict__ h1b,
                                                   const float* __restrict__ asad,
                                                   const int* __restrict__ row_ptr,
                                                   const int* __restrict__ rowend,
                                                   const int* __restrict__ col,
                                                   const float* __restrict__ b1,
                                                   u16* __restrict__ hin2b, int N) {
    __shared__ float la[4][128][4];
    __shared__ int   lc[4][128];
    int idx = blockIdx.x * blockDim.x + threadIdx.x;
    int v = idx >> 6; if (v > N - 1) v = N - 1;
    int lane = idx & 63;
    int node = threadIdx.x >> 6;
    int head = lane >> 4, l15 = lane & 15;
    float adst = asad[(size_t)v * 8 + 4 + head];
    int beg = row_ptr[v], end = rowend[v];
    int deg = end - beg;
    bool fast = (deg <= 128);
    float m = -1e30f, l = 0.f;
    if (fast) {
        float e[8]; int u[8];
#pragma unroll
        for (int i = 0; i < 8; ++i) {
            int p = beg + l15 + i * 16;
            float ev = -1e30f; int uu = 0;
            if (p < end) {
                uu = col[p];
                float tv = asad[(size_t)uu * 8 + head] + adst;
                ev = tv > 0.f ? tv : NEG * tv;
            }
            e[i] = ev; u[i] = uu;
        }
        m = e[0];
#pragma unroll
        for (int i = 1; i < 8; ++i) m = fmaxf(m, e[i]);
#pragma unroll
        for (int mask = 1; mask < 16; mask <<= 1) m = fmaxf(m, __shfl_xor(m, mask, 64));
#pragma unroll
        for (int i = 0; i < 8; ++i) {
            int j = l15 + i * 16;
            if (beg + j < end) {
                float a = __expf(e[i] - m);
                l += a;
                la[node][j][head] = a;
                if (head == 0) lc[node][j] = u[i];
            }
        }
#pragma unroll
        for (int mask = 1; mask < 16; mask <<= 1) l += __shfl_xor(l, mask, 64);
    } else {
        for (int p = beg + l15; p < end; p += 16) {
            float tv = asad[(size_t)col[p] * 8 + head] + adst;
            tv = tv > 0.f ? tv : NEG * tv;
            m = fmaxf(m, tv);
        }
#pragma unroll
        for (int mask = 1; mask < 16; mask <<= 1) m = fmaxf(m, __shfl_xor(m, mask, 64));
        for (int p = beg + l15; p < end; p += 16) {
            float tv = asad[(size_t)col[p] * 8 + head] + adst;
            tv = tv > 0.f ? tv : NEG * tv;
            l += __expf(tv - m);
        }
#pragma unroll
        for (int mask = 1; mask < 16; mask <<= 1) l += __shfl_xor(l, mask, 64);
    }
    __syncthreads();
    float inv = 1.f / (l + 1e-16f);

    float ax = 0.f, ay = 0.f, az = 0.f, aw = 0.f;
    if (fast) {
        int j = 0;
        for (; j + 3 < deg; j += 4) {
            float a0 = la[node][j + 0][head];
            float a1 = la[node][j + 1][head];
            float a2 = la[node][j + 2][head];
            float a3 = la[node][j + 3][head];
            int u0 = lc[node][j + 0], u1 = lc[node][j + 1];
            int u2 = lc[node][j + 2], u3 = lc[node][j + 3];
            ushort4 h0 = *reinterpret_cast<const ushort4*>(h1b + (size_t)u0 * 256 + lane * 4);
            ushort4 h1 = *reinterpret_cast<const ushort4*>(h1b + (size_t)u1 * 256 + lane * 4);
            ushort4 h2 = *reinterpret_cast<const ushort4*>(h1b + (size_t)u2 * 256 + lane * 4);
            ushort4 h3 = *reinterpret_cast<const ushort4*>(h1b + (size_t)u3 * 256 + lane * 4);
            ax += a0 * bf2f(h0.x) + a1 * bf2f(h1.x) + a2 * bf2f(h2.x) + a3 * bf2f(h3.x);
            ay += a0 * bf2f(h0.y) + a1 * bf2f(h1.y) + a2 * bf2f(h2.y) + a3 * bf2f(h3.y);
            az += a0 * bf2f(h0.z) + a1 * bf2f(h1.z) + a2 * bf2f(h2.z) + a3 * bf2f(h3.z);
            aw += a0 * bf2f(h0.w) + a1 * bf2f(h1.w) + a2 * bf2f(h2.w) + a3 * bf2f(h3.w);
        }
        for (; j < deg; ++j) {
            float a = la[node][j][head];
            int u = lc[node][j];
            ushort4 hv = *reinterpret_cast<const ushort4*>(h1b + (size_t)u * 256 + lane * 4);
            ax += a * bf2f(hv.x);
            ay += a * bf2f(hv.y);
            az += a * bf2f(hv.z);
            aw += a * bf2f(hv.w);
        }
    } else {
        for (int p = beg; p < end; ++p) {
            int u = col[p];
            float tv = asad[(size_t)u * 8 + head] + adst;
            tv = tv > 0.f ? tv : NEG * tv;
            float a = __expf(tv - m);
            ushort4 hv = *reinterpret_cast<const ushort4*>(h1b + (size_t)u * 256 + lane * 4);
            ax += a * bf2f(hv.x);
            ay += a * bf2f(hv.y);
            az += a * bf2f(hv.z);
            aw += a * bf2f(hv.w);
        }
    }
    int c = lane * 4;
    ushort4 o;
    o.x = f2bf(fmaxf(ax * inv + b1[c + 0], 0.f));
    o.y = f2bf(fmaxf(ay * inv + b1[c + 1], 0.f));
    o.z = f2bf(fmaxf(az * inv + b1[c + 2], 0.f));
    o.w = f2bf(fmaxf(aw * inv + b1[c + 3], 0.f));
    *reinterpret_cast<ushort4*>(hin2b + (size_t)v * 256 + c) = o;
}

// ---------------- GEMM2 MFMA: weight-stationary LDS (48x256 bf16, att folded) ----
__global__ __launch_bounds__(512) void gemm2_mfma(const u16* __restrict__ hin2b,
                                                  const u16* __restrict__ w2x,
                                                  u16* __restrict__ h2b,
                                                  float* __restrict__ as2,
                                                  float* __restrict__ ad2, int N) {
    __shared__ __align__(16) u16 wl[48 * 264];
    for (int f = threadIdx.x; f < 48 * 32; f += 512) {
        int r = f >> 5, cc = f & 31;
        *reinterpret_cast<uint4*>(&wl[r * 264 + cc * 8]) =
            *reinterpret_cast<const uint4*>(w2x + r * 256 + cc * 8);
    }
    __syncthreads();

    int wave = threadIdx.x >> 6, lane = threadIdx.x & 63;
    int g = lane >> 4, l15 = lane & 15;
    int ntiles = (N + 15) >> 4;
    for (int tile = blockIdx.x * 8 + wave; tile < ntiles; tile += gridDim.x * 8) {
        int r0 = tile << 4;
        int arow = r0 + l15; if (arow > N - 1) arow = N - 1;
        const u16* hp = hin2b + (size_t)arow * 256 + g * 8;

        f32x4 acc[3];
#pragma unroll
        for (int n = 0; n < 3; ++n) acc[n] = (f32x4){0.f, 0.f, 0.f, 0.f};

#pragma unroll
        for (int ks = 0; ks < 8; ++ks) {
            bf16x8 af = *reinterpret_cast<const bf16x8*>(hp + ks * 32);
#pragma unroll
            for (int n = 0; n < 3; ++n) {
                bf16x8 bf = *reinterpret_cast<const bf16x8*>(&wl[(n * 16 + l15) * 264 + ks * 32 + g * 8]);
                acc[n] = __builtin_amdgcn_mfma_f32_16x16x32_bf16(af, bf, acc[n], 0, 0, 0);
            }
        }

#pragma unroll
        for (int reg = 0; reg < 4; ++reg) {
            int grow = r0 + g * 4 + reg;
            if (grow < N) {
                h2b[(size_t)grow * 32 + l15]      = f2bf(acc[0][reg]);
                h2b[(size_t)grow * 32 + 16 + l15] = f2bf(acc[1][reg]);
                if (l15 == 0) as2[grow] = acc[2][reg];
                if (l15 == 1) ad2[grow] = acc[2][reg];
            }
        }
    }
}

// ---------------- conv2 fused: stats caches alpha+col in LDS, then gather --------
__global__ __launch_bounds__(256) void conv2_fused(const u16* __restrict__ h2b,
                                                   const float* __restrict__ as2,
                                                   const float* __restrict__ ad2,
                                                   const int* __restrict__ row_ptr,
                                                   const int* __restrict__ rowend,
                                                   const int* __restrict__ col,
                                                   const float* __restrict__ b2,
                                                   float* __restrict__ out2, int N) {
    __shared__ float la[8][128];
    __shared__ int   lc[8][128];
    int idx = blockIdx.x * blockDim.x + threadIdx.x;
    int v = idx >> 5; if (v > N - 1) v = N - 1;
    int lane = idx & 31;
    int node = threadIdx.x >> 5;
    float adst = ad2[v];
    int beg = row_ptr[v], end = rowend[v];
    int deg = end - beg;
    bool fast = (deg <= 128);
    float m = -1e30f, l = 0.f;
    if (fast) {
        float e[4]; int u[4];
#pragma unroll
        for (int i = 0; i < 4; ++i) {
            int p = beg + lane + i * 32;
            float ev = -1e30f; int uu = 0;
            if (p < end) {
                uu = col[p];
                float tv = as2[uu] + adst;
                ev = tv > 0.f ? tv : NEG * tv;
            }
            e[i] = ev; u[i] = uu;
        }
        m = fmaxf(fmaxf(e[0], e[1]), fmaxf(e[2], e[3]));
#pragma unroll
        for (int mask = 1; mask < 32; mask <<= 1) m = fmaxf(m, __shfl_xor(m, mask, 64));
#pragma unroll
        for (int i = 0; i < 4; ++i) {
            int j = lane + i * 32;
            if (beg + j < end) {
                float a = __expf(e[i] - m);
                l += a;
                la[node][j] = a;
                lc[node][j] = u[i];
            }
        }
#pragma unroll
        for (int mask = 1; mask < 32; mask <<= 1) l += __shfl_xor(l, mask, 64);
    } else {
        for (int p = beg + lane; p < end; p += 32) {
            float tv = as2[col[p]] + adst;
            tv = tv > 0.f ? tv : NEG * tv;
            m = fmaxf(m, tv);
        }
#pragma unroll
        for (int mask = 1; mask < 32; mask <<= 1) m = fmaxf(m, __shfl_xor(m, mask, 64));
        for (int p = beg + lane; p < end; p += 32) {
            float tv = as2[col[p]] + adst;
            tv = tv > 0.f ? tv : NEG * tv;
            l += __expf(tv - m);
        }
#pragma unroll
        for (int mask = 1; mask < 32; mask <<= 1) l += __shfl_xor(l, mask, 64);
    }
    __syncthreads();
    float inv = 1.f / (l + 1e-16f);

    float acc = 0.f;
    if (fast) {
        int j = 0;
        for (; j + 3 < deg; j += 4) {
            float a0 = la[node][j + 0], a1 = la[node][j + 1];
            float a2 = la[node][j + 2], a3 = la[node][j + 3];
            int u0 = lc[node][j + 0], u1 = lc[node][j + 1];
            int u2 = lc[node][j + 2], u3 = lc[node][j + 3];
            acc += a0 * bf2f(h2b[(size_t)u0 * 32 + lane])
                 + a1 * bf2f(h2b[(size_t)u1 * 32 + lane])
                 + a2 * bf2f(h2b[(size_t)u2 * 32 + lane])
                 + a3 * bf2f(h2b[(size_t)u3 * 32 + lane]);
        }
        for (; j < deg; ++j)
            acc += la[node][j] * bf2f(h2b[(size_t)lc[node][j] * 32 + lane]);
    } else {
        for (int p = beg; p < end; ++p) {
            int u = col[p];
            float tv = as2[u] + adst;
            tv = tv > 0.f ? tv : NEG * tv;
            acc += __expf(tv - m) * bf2f(h2b[(size_t)u * 32 + lane]);
        }
    }
    out2[(size_t)v * 32 + lane] = acc * inv + b2[lane];
}

// ---------------- pooling + FC head ----------------
__global__ __launch_bounds__(256) void pool_fc(const float* __restrict__ out2,
                                               const int* __restrict__ batch,
                                               const float* __restrict__ fc1w,
                                               const float* __restrict__ fc1b,
                                               const float* __restrict__ fc2w,
                                               const float* __restrict__ fc2b,
                                               float* __restrict__ out, int N) {
    int g = blockIdx.x;
    int lo = 0, hi = N;
    while (lo < hi) { int mid = (lo + hi) >> 1; if (batch[mid] < g) lo = mid + 1; else hi = mid; }
    int s = lo;
    lo = 0; hi = N;
    while (lo < hi) { int mid = (lo + hi) >> 1; if (batch[mid] < g + 1) lo = mid + 1; else hi = mid; }
    int e = lo;

    int c = threadIdx.x & 31, grp = threadIdx.x >> 5;
    float sum = 0.f;
    for (int r = s + grp; r < e; r += 8) sum += out2[(size_t)r * 32 + c];
    __shared__ float part[8][32];
    part[grp][c] = sum;
    __syncthreads();
    __shared__ float g0[32];
    if (grp == 0) {
        float tot = 0.f;
#pragma unroll
        for (int q = 0; q < 8; ++q) tot += part[q][c];
        float cnt = (float)(e - s);
        g0[c] = fmaxf(tot / fmaxf(cnt, 1.0f), 0.f);
    }
    __syncthreads();
    __shared__ float z1[16];
    if (threadIdx.x < 16) {
        float a = fc1b[threadIdx.x];
        for (int k = 0; k < 32; ++k) a += g0[k] * fc1w[k * 16 + threadIdx.x];
        z1[threadIdx.x] = fmaxf(a, 0.f);
    }
    __syncthreads();
    if (threadIdx.x < 16) {
        float a = fc2b[threadIdx.x];
        for (int k = 0; k < 16; ++k) a += z1[k] * fc2w[k * 16 + threadIdx.x];
        out[g * 16 + threadIdx.x] = fmaxf(a, 0.f);
    }
}

// ---------------- host launcher ----------------
extern "C" void kernel_launch(void* const* d_in, const int* in_sizes, int n_in,
                              void* d_out, int out_size, void* d_ws, size_t ws_size,
                              hipStream_t stream) {
    const float* x      = (const float*)d_in[0];
    const int*   ei     = (const int*)d_in[1];
    const int*   batch  = (const int*)d_in[2];
    const float* W1     = (const float*)d_in[3];
    const float* att_s1 = (const float*)d_in[4];
    const float* att_d1 = (const float*)d_in[5];
    const float* b1     = (const float*)d_in[6];
    const float* W2     = (const float*)d_in[7];
    const float* att_s2 = (const float*)d_in[8];
    const float* att_d2 = (const float*)d_in[9];
    const float* b2     = (const float*)d_in[10];
    const float* fc1w   = (const float*)d_in[11];
    const float* fc1b   = (const float*)d_in[12];
    const float* fc2w   = (const float*)d_in[13];
    const float* fc2b   = (const float*)d_in[14];
    float* out = (float*)d_out;

    int N = in_sizes[0] / 256;      // 50000
    int E = in_sizes[1] / 2;        // 800000
    int ET = E + N;
    int NBK = (N + 63) >> 6;        // 782
    int nchunks = (ET + SCHUNK - 1) / SCHUNK;   // 416

    char* ws = (char*)d_ws;
    size_t off = 0;
    auto alloc = [&](size_t bytes) { size_t o = off; off = (off + bytes + 255) & ~255ULL; return o; };
    u16*  w1x    = (u16*)(ws + alloc(272 * 256 * 2));
    u16*  w2x    = (u16*)(ws + alloc(48 * 256 * 2));
    u16*  h1b    = (u16*)(ws + alloc((size_t)N * 256 * 2));
    float* asad  = (float*)(ws + alloc((size_t)N * 8 * 4));
    u16*  hin2b  = (u16*)(ws + alloc((size_t)N * 256 * 2));
    u16*  h2b    = (u16*)(ws + alloc((size_t)N * 32 * 2));
    float* as2   = (float*)(ws + alloc((size_t)N * 4));
    float* ad2   = (float*)(ws + alloc((size_t)N * 4));
    float* out2  = (float*)(ws + alloc((size_t)N * 32 * 4));
    int* row_ptr = (int*)(ws + alloc((size_t)N * 4));
    int* rowend  = (int*)(ws + alloc((size_t)N * 4));
    int* col     = (int*)(ws + alloc((size_t)NBK * CAP * 4));
    int* bktcur  = (int*)(ws + alloc((size_t)NBK * 4));
    u32* ebuf    = (u32*)(ws + alloc((size_t)NBK * CAP * 4));
    (void)ws_size; (void)n_in; (void)out_size;

    // prep: w1x + w2x + zero bktcur
    prep_all<<<257, 256, 0, stream>>>(W1, att_s1, att_d1, w1x, W2, att_s2, att_d2, w2x, bktcur, NBK);

    // fused gemm1 + edge scatter (mutually independent work, co-scheduled)
    gemm1_and_scatter<<<256 + nchunks, 512, 0, stream>>>(x, w1x, h1b, asad, N,
                                                         ei, bktcur, ebuf, E, ET, NBK);

    // per-bucket CSR finalize
    bucket_csr_pad<<<NBK, 256, 0, stream>>>(ebuf, bktcur, row_ptr, rowend, col, N);

    // conv1
    conv1_fused<<<(N * 64 + 255) / 256, 256, 0, stream>>>(h1b, asad, row_ptr, rowend, col, b1, hin2b, N);

    // conv2
    gemm2_mfma<<<256, 512, 0, stream>>>(hin2b, w2x, h2b, as2, ad2, N);
    conv2_fused<<<(N * 32 + 255) / 256, 256, 0, stream>>>(h2b, as2, ad2, row_ptr, rowend, col, b2, out2, N);

    // pool + fc
    pool_fc<<<64, 256, 0, stream>>>(out2, batch, fc1w, fc1b, fc2w, fc2b, out, N);
}